// Round 12
// baseline (294.861 us; speedup 1.0000x reference)
//
#include <hip/hip_runtime.h>
#include <hip/hip_bf16.h>

// Rulebook sparse conv, R11 (resubmit after broker timeout).
//   (1) Non-temporal vals stream: nt-store in pass1, nt-load in pass2 ->
//       xb stays L3-resident, gather becomes L3-hit (R10 insight: 169MB vals
//       writes were evicting the 19.2MB xb table, FETCH 95MB >> 35MB ideal).
//   (2) pass2: wave-per-row, 4 rules in flight x 16 ch-slices, shfl_xor
//       butterfly reduce (ceil-waste 27% vs max-of-8 60%).
//   (3) rankl gone: k_count = pure count; scan1 writes cursor copy; pass1
//       claims rank via atomicAdd(&cursor[row],1) overlapped with DMA.

typedef __bf16 bf16x8_t __attribute__((ext_vector_type(8)));
typedef __bf16 bf16x2_t __attribute__((ext_vector_type(2)));
typedef float f32x4_t __attribute__((ext_vector_type(4)));
typedef int i32x4_t __attribute__((ext_vector_type(4)));
typedef short s16x4_t __attribute__((ext_vector_type(4)));

#define KOFF 27
#define RULES 50000
#define KR (KOFF * RULES) /* 1,350,000 */
#define CIN 64
#define COUT 64
#define NIN 150000
#define NOUT 150000

// pass1 tile
#define BR1 128
#define BPK1 ((RULES + BR1 - 1) / BR1) /* 391 */
// fallback tile
#define BRF 256
#define BPKF ((RULES + BRF - 1) / BRF) /* 196 */

#define NB1 ((NOUT + 1023) / 1024) /* 147 scan blocks */

// ws layout (bytes, 256-aligned)
#define OFF_OFF 0ull           /* int off[NOUT+1] */
#define OFF_BSUM 600064ull     /* int bsum[NB1] */
#define OFF_BSCAN 600832ull    /* int bscan[NB1] */
#define OFF_CUR 601600ull      /* int cursor[NOUT] */
#define OFF_XB 1201664ull      /* bf16 xb[NIN][64] */
#define OFF_VALS 20401920ull   /* bf16 vals[KR][64] */
#define WS_FULL (20401920ull + 172800000ull) /* 193.2 MB */

__device__ __forceinline__ void gload_lds16(const void* g, void* l) {
  __builtin_amdgcn_global_load_lds(
      (const __attribute__((address_space(1))) unsigned int*)g,
      (__attribute__((address_space(3))) unsigned int*)l, 16, 0, 0);
}

__device__ __forceinline__ float bf16bits_to_f32(short b) {
  return __uint_as_float(((unsigned)(unsigned short)b) << 16);
}

// ---------------- x -> bf16 (nt reads), fused with off zeroing ----------------
__global__ __launch_bounds__(256) void k_cvt_zero(const float* __restrict__ x,
                                                  __bf16* __restrict__ xb,
                                                  int* __restrict__ cnt) {
  const int i = blockIdx.x * 256 + threadIdx.x;
  if (i < NIN * CIN / 8) {
    const f32x4_t f0 =
        __builtin_nontemporal_load(reinterpret_cast<const f32x4_t*>(x) + i * 2);
    const f32x4_t f1 = __builtin_nontemporal_load(
        reinterpret_cast<const f32x4_t*>(x) + i * 2 + 1);
    bf16x8_t v;
    v[0] = (__bf16)f0[0]; v[1] = (__bf16)f0[1]; v[2] = (__bf16)f0[2]; v[3] = (__bf16)f0[3];
    v[4] = (__bf16)f1[0]; v[5] = (__bf16)f1[1]; v[6] = (__bf16)f1[2]; v[7] = (__bf16)f1[3];
    reinterpret_cast<bf16x8_t*>(xb)[i] = v;  // cached: keep xb in L3
  }
  if (i <= NOUT) cnt[i] = 0;
}

// ---------------- sort ----------------
__global__ __launch_bounds__(256) void k_count(const int* __restrict__ out_idx,
                                               int* __restrict__ cnt) {
  const int i = blockIdx.x * 256 + threadIdx.x;
  if (i < KR / 4) {
    const int4 v = reinterpret_cast<const int4*>(out_idx)[i];
    atomicAdd(&cnt[v.x], 1);
    atomicAdd(&cnt[v.y], 1);
    atomicAdd(&cnt[v.z], 1);
    atomicAdd(&cnt[v.w], 1);
  }
}

__global__ __launch_bounds__(1024) void k_scan1(int* __restrict__ off,
                                                int* __restrict__ cursor,
                                                int* __restrict__ bsum) {
  __shared__ int s[1024];
  const int t = threadIdx.x;
  const int i = blockIdx.x * 1024 + t;
  const int v = (i < NOUT) ? off[i] : 0;
  s[t] = v;
  __syncthreads();
#pragma unroll
  for (int d = 1; d < 1024; d <<= 1) {
    const int u = (t >= d) ? s[t - d] : 0;
    __syncthreads();
    s[t] += u;
    __syncthreads();
  }
  if (i < NOUT) {
    const int ex = s[t] - v;  // exclusive within block
    off[i] = ex;
    cursor[i] = ex;  // pass1 claims ranks from this copy
  }
  if (t == 1023) bsum[blockIdx.x] = s[1023];
}

// tiny: exclusive scan of 147 block sums -> bscan
__global__ __launch_bounds__(256) void k_scan2(const int* __restrict__ bsum,
                                               int* __restrict__ bscan, int nb) {
  __shared__ int s[256];
  const int t = threadIdx.x;
  const int v = (t < nb) ? bsum[t] : 0;
  s[t] = v;
  __syncthreads();
#pragma unroll
  for (int d = 1; d < 256; d <<= 1) {
    const int u = (t >= d) ? s[t - d] : 0;
    __syncthreads();
    s[t] += u;
    __syncthreads();
  }
  if (t < nb) bscan[t] = s[t] - v;  // exclusive
}

// ---------------- pass 1: bf16 gather via global_load_lds ----------------
__global__ __launch_bounds__(256) void pass1_bf16(
    const __bf16* __restrict__ xb, const float* __restrict__ w,
    const int* __restrict__ in_idx, const int* __restrict__ out_idx,
    int* __restrict__ cursor, const int* __restrict__ bscan,
    __bf16* __restrict__ vals) {
  __shared__ char lds[BR1 * 128 + 64 * 128];  // 24 KB
  __shared__ int lds_dst[BR1];
  char* const Abase = lds;
  char* const Bbase = lds + BR1 * 128;

  const int bid = blockIdx.x;
  const int k = bid / BPK1;
  const int rblk = bid - k * BPK1;
  const int rule0 = rblk * BR1;
  const int t = threadIdx.x;
  const int wid = t >> 6;
  const int lane = t & 63;

  // stage A: per-lane pre-swizzled source, linear LDS dest
  {
    const int rowInWave = lane >> 3;
    const int srcChunk = (lane & 7) ^ rowInWave;
    const int* idxBase = in_idx + (size_t)k * RULES;
#pragma unroll
    for (int it = 0; it < 4; ++it) {
      const int rbase = it * 32 + wid * 8;
      int rule = rule0 + rbase + rowInWave;
      if (rule > RULES - 1) rule = RULES - 1;  // clamp: finite data, skipped later
      const int src = idxBase[rule];
      const __bf16* gp = xb + ((size_t)src << 6) + (srcChunk << 3);
      gload_lds16(gp, Abase + rbase * 128 + lane * 16);
    }
  }

  // dst claim (overlaps gather DMA): rank = atomicAdd on local-prefix cursor
  if (t < BR1) {
    const int rule = rule0 + t;
    if (rule < RULES) {
      const size_t gi = (size_t)k * RULES + rule;
      const int orow = out_idx[gi];
      const int local = atomicAdd(&cursor[orow], 1);
      lds_dst[t] = bscan[orow >> 10] + local;
    }
  }

  // stage B: W_k^T -> LDS[o][c] bf16, swizzled
  {
    const int c = t >> 2;
    const int o0 = (t & 3) * 16;
    const float* wp = w + ((size_t)k * CIN + c) * COUT + o0;
#pragma unroll
    for (int j4 = 0; j4 < 4; ++j4) {
      const float4 f = *reinterpret_cast<const float4*>(wp + j4 * 4);
#pragma unroll
      for (int e = 0; e < 4; ++e) {
        const int o = o0 + j4 * 4 + e;
        const float val = (e == 0) ? f.x : (e == 1) ? f.y : (e == 2) ? f.z : f.w;
        const int addr = o * 128 + ((c * 2) ^ ((o & 7) << 4));
        *reinterpret_cast<__bf16*>(Bbase + addr) = (__bf16)val;
      }
    }
  }

  __syncthreads();

  const int rA = lane & 15;
  const int g = lane >> 4;

  bf16x8_t af[2][2];
  bf16x8_t bfr[4][2];
#pragma unroll
  for (int m = 0; m < 2; ++m)
#pragma unroll
    for (int kk = 0; kk < 2; ++kk) {
      const int r = wid * 32 + m * 16 + rA;
      const int colByte = (kk * 64 + g * 16) ^ ((r & 7) << 4);
      af[m][kk] = *reinterpret_cast<const bf16x8_t*>(Abase + r * 128 + colByte);
    }
#pragma unroll
  for (int n = 0; n < 4; ++n)
#pragma unroll
    for (int kk = 0; kk < 2; ++kk) {
      const int o = n * 16 + rA;
      const int colByte = (kk * 64 + g * 16) ^ ((o & 7) << 4);
      bfr[n][kk] = *reinterpret_cast<const bf16x8_t*>(Bbase + o * 128 + colByte);
    }

  __syncthreads();  // frag reads done; Abase reused for D staging

  f32x4_t acc[2][4];
#pragma unroll
  for (int m = 0; m < 2; ++m)
#pragma unroll
    for (int n = 0; n < 4; ++n)
#pragma unroll
      for (int e = 0; e < 4; ++e) acc[m][n][e] = 0.0f;

#pragma unroll
  for (int kk = 0; kk < 2; ++kk)
#pragma unroll
    for (int m = 0; m < 2; ++m)
#pragma unroll
      for (int n = 0; n < 4; ++n)
        acc[m][n] = __builtin_amdgcn_mfma_f32_16x16x32_bf16(
            af[m][kk], bfr[n][kk], acc[m][n], 0, 0, 0);

  // stage D -> LDS bf16 rows (swizzled)
  const bool evenLane = (rA & 1) == 0;
#pragma unroll
  for (int m = 0; m < 2; ++m) {
#pragma unroll
    for (int j = 0; j < 4; ++j) {
      const int rr = wid * 32 + m * 16 + g * 4 + j;
      float mine[4], other[4];
#pragma unroll
      for (int n = 0; n < 4; ++n) {
        mine[n] = acc[m][n][j];
        other[n] = __shfl_xor(mine[n], 1, 64);
      }
      const int swz = (rr & 7) << 4;
      if (evenLane) {
#pragma unroll
        for (int n = 0; n < 2; ++n) {
          bf16x2_t p; p[0] = (__bf16)mine[n]; p[1] = (__bf16)other[n];
          const int col = n * 16 + rA;
          *reinterpret_cast<bf16x2_t*>(Abase + rr * 128 + ((col * 2) ^ swz)) = p;
        }
      } else {
#pragma unroll
        for (int n = 2; n < 4; ++n) {
          bf16x2_t p; p[0] = (__bf16)other[n]; p[1] = (__bf16)mine[n];
          const int col = n * 16 + rA - 1;
          *reinterpret_cast<bf16x2_t*>(Abase + rr * 128 + ((col * 2) ^ swz)) = p;
        }
      }
    }
  }

  __syncthreads();

  // writeback: NON-TEMPORAL scatter of full 128B rows (keep xb in L3)
  {
    const int chunk = t & 7;
    const int r0 = t >> 3;
#pragma unroll
    for (int pass = 0; pass < 4; ++pass) {
      const int r = r0 + pass * 32;
      const int rule = rule0 + r;
      if (rule < RULES) {
        const int dst = lds_dst[r];
        const i32x4_t v = *reinterpret_cast<const i32x4_t*>(
            Abase + r * 128 + ((chunk * 16) ^ ((r & 7) << 4)));
        __builtin_nontemporal_store(
            v, reinterpret_cast<i32x4_t*>(vals + (size_t)dst * COUT + chunk * 8));
      }
    }
  }
}

// ---------------- pass 2 v6: wave-per-row, 4 rules in flight ----------
// lane = (rp 0..3) * 16 + (cs 0..15); each lane reads 8B (4 ch) per rule.
__global__ __launch_bounds__(256) void pass2_kernel(
    const __bf16* __restrict__ vals, const int* __restrict__ off,
    const int* __restrict__ bscan, const float* __restrict__ bias,
    float* __restrict__ out) {
  const int t = threadIdx.x;
  const int row = blockIdx.x * 4 + (t >> 6);  // NOUT % 4 == 0
  const int lane = t & 63;
  const int rp = lane >> 4;  // rule-parallel 0..3
  const int cs = lane & 15;  // channel slice (4 ch)

  const int s = off[row] + bscan[row >> 10];
  const int e = (row + 1 < NOUT) ? off[row + 1] + bscan[(row + 1) >> 10] : KR;

  float a0 = 0.0f, a1 = 0.0f, a2 = 0.0f, a3 = 0.0f;
  const short* vp =
      reinterpret_cast<const short*>(vals) + (size_t)(s + rp) * COUT + cs * 4;
  for (int j = s + rp; j < e; j += 4, vp += 4 * COUT) {
    const s16x4_t v =
        __builtin_nontemporal_load(reinterpret_cast<const s16x4_t*>(vp));
    a0 += bf16bits_to_f32(v[0]);
    a1 += bf16bits_to_f32(v[1]);
    a2 += bf16bits_to_f32(v[2]);
    a3 += bf16bits_to_f32(v[3]);
  }

  // butterfly over rp lanes (lane^16, lane^32)
  a0 += __shfl_xor(a0, 16, 64); a1 += __shfl_xor(a1, 16, 64);
  a2 += __shfl_xor(a2, 16, 64); a3 += __shfl_xor(a3, 16, 64);
  a0 += __shfl_xor(a0, 32, 64); a1 += __shfl_xor(a1, 32, 64);
  a2 += __shfl_xor(a2, 32, 64); a3 += __shfl_xor(a3, 32, 64);

  if (rp == 0) {
    const f32x4_t b = reinterpret_cast<const f32x4_t*>(bias)[cs];
    f32x4_t o;
    o[0] = a0 + b[0]; o[1] = a1 + b[1]; o[2] = a2 + b[2]; o[3] = a3 + b[3];
    __builtin_nontemporal_store(
        o, reinterpret_cast<f32x4_t*>(out + (size_t)row * COUT + cs * 4));
  }
}

// ---------------- fallback (tiny ws): atomic scatter ----------------
__global__ __launch_bounds__(256) void init_out_kernel(
    const float* __restrict__ bias, float* __restrict__ out, int total4) {
  const int i = blockIdx.x * blockDim.x + threadIdx.x;
  if (i < total4) {
    const float4 v = reinterpret_cast<const float4*>(bias)[i & 15];
    reinterpret_cast<float4*>(out)[i] = v;
  }
}

__global__ __launch_bounds__(256) void spconv_atomic_kernel(
    const float* __restrict__ x, const float* __restrict__ w,
    const int* __restrict__ in_idx, const int* __restrict__ out_idx,
    float* __restrict__ out) {
  __shared__ char lds[256 * 128 + 64 * 128];
  char* const Abase = lds;
  char* const Bbase = lds + 256 * 128;

  const int bid = blockIdx.x;
  const int k = bid / BPKF;
  const int rblk = bid - k * BPKF;
  const int rule0 = rblk * BRF;
  const int t = threadIdx.x;

  {
    const int chunk = t & 7;
    const int r0 = t >> 3;
#pragma unroll
    for (int pass = 0; pass < 8; ++pass) {
      const int r = r0 + pass * 32;
      const int rule = rule0 + r;
      bf16x8_t v;
      if (rule < RULES) {
        const int src = in_idx[(size_t)k * RULES + rule];
        const float* p = x + (size_t)src * CIN + chunk * 8;
        const float4 f0 = *reinterpret_cast<const float4*>(p);
        const float4 f1 = *reinterpret_cast<const float4*>(p + 4);
        v[0] = (__bf16)f0.x; v[1] = (__bf16)f0.y;
        v[2] = (__bf16)f0.z; v[3] = (__bf16)f0.w;
        v[4] = (__bf16)f1.x; v[5] = (__bf16)f1.y;
        v[6] = (__bf16)f1.z; v[7] = (__bf16)f1.w;
      } else {
#pragma unroll
        for (int e = 0; e < 8; ++e) v[e] = (__bf16)0.0f;
      }
      const int colByte = (chunk * 16) ^ ((r & 7) << 4);
      *reinterpret_cast<bf16x8_t*>(Abase + r * 128 + colByte) = v;
    }
  }
  {
    const int c = t >> 2;
    const int o0 = (t & 3) * 16;
    const float* wp = w + ((size_t)k * CIN + c) * COUT + o0;
#pragma unroll
    for (int j4 = 0; j4 < 4; ++j4) {
      const float4 f = *reinterpret_cast<const float4*>(wp + j4 * 4);
#pragma unroll
      for (int e = 0; e < 4; ++e) {
        const int o = o0 + j4 * 4 + e;
        const float val = (e == 0) ? f.x : (e == 1) ? f.y : (e == 2) ? f.z : f.w;
        const int addr = o * 128 + ((c * 2) ^ ((o & 7) << 4));
        *reinterpret_cast<__bf16*>(Bbase + addr) = (__bf16)val;
      }
    }
  }
  __syncthreads();

  const int wid = t >> 6;
  const int l = t & 63;
  const int rA = l & 15;
  const int g = l >> 4;

  bf16x8_t af[4][2];
  bf16x8_t bfr[4][2];
#pragma unroll
  for (int m = 0; m < 4; ++m)
#pragma unroll
    for (int kk = 0; kk < 2; ++kk) {
      const int r = wid * 64 + m * 16 + rA;
      const int colByte = (kk * 64 + g * 16) ^ ((r & 7) << 4);
      af[m][kk] = *reinterpret_cast<const bf16x8_t*>(Abase + r * 128 + colByte);
    }
#pragma unroll
  for (int n = 0; n < 4; ++n)
#pragma unroll
    for (int kk = 0; kk < 2; ++kk) {
      const int o = n * 16 + rA;
      const int colByte = (kk * 64 + g * 16) ^ ((o & 7) << 4);
      bfr[n][kk] = *reinterpret_cast<const bf16x8_t*>(Bbase + o * 128 + colByte);
    }

  f32x4_t acc[4][4];
#pragma unroll
  for (int m = 0; m < 4; ++m)
#pragma unroll
    for (int n = 0; n < 4; ++n)
#pragma unroll
      for (int e = 0; e < 4; ++e) acc[m][n][e] = 0.0f;

#pragma unroll
  for (int kk = 0; kk < 2; ++kk)
#pragma unroll
    for (int m = 0; m < 4; ++m)
#pragma unroll
      for (int n = 0; n < 4; ++n)
        acc[m][n] = __builtin_amdgcn_mfma_f32_16x16x32_bf16(
            af[m][kk], bfr[n][kk], acc[m][n], 0, 0, 0);

#pragma unroll
  for (int m = 0; m < 4; ++m)
#pragma unroll
    for (int j = 0; j < 4; ++j) {
      const int rr = wid * 64 + m * 16 + g * 4 + j;
      const int rule = rule0 + rr;
      if (rule < RULES) {
        const int orow = out_idx[(size_t)k * RULES + rule];
        float* op = out + (size_t)orow * COUT + rA;
#pragma unroll
        for (int n = 0; n < 4; ++n) atomicAdd(op + n * 16, acc[m][n][j]);
      }
    }
}

// ---------------- launch ----------------
extern "C" void kernel_launch(void* const* d_in, const int* in_sizes, int n_in,
                              void* d_out, int out_size, void* d_ws, size_t ws_size,
                              hipStream_t stream) {
  const float* x = (const float*)d_in[0];
  const float* w = (const float*)d_in[1];
  const float* bias = (const float*)d_in[2];
  const int* in_idx = (const int*)d_in[3];
  const int* out_idx = (const int*)d_in[4];
  float* out = (float*)d_out;

  if (ws_size >= WS_FULL) {
    char* ws = (char*)d_ws;
    int* off = (int*)(ws + OFF_OFF);
    int* bsum = (int*)(ws + OFF_BSUM);
    int* bscan = (int*)(ws + OFF_BSCAN);
    int* cursor = (int*)(ws + OFF_CUR);
    __bf16* xb = (__bf16*)(ws + OFF_XB);
    __bf16* vals = (__bf16*)(ws + OFF_VALS);

    k_cvt_zero<<<(NIN * CIN / 8 + 255) / 256, 256, 0, stream>>>(x, xb, off);
    k_count<<<(KR / 4 + 255) / 256, 256, 0, stream>>>(out_idx, off);
    k_scan1<<<NB1, 1024, 0, stream>>>(off, cursor, bsum);
    k_scan2<<<1, 256, 0, stream>>>(bsum, bscan, NB1);
    pass1_bf16<<<KOFF * BPK1, 256, 0, stream>>>(xb, w, in_idx, out_idx, cursor,
                                                bscan, vals);
    pass2_kernel<<<NOUT / 4, 256, 0, stream>>>(vals, off, bscan, bias, out);
  } else {
    const int total4 = NOUT * COUT / 4;
    init_out_kernel<<<(total4 + 255) / 256, 256, 0, stream>>>(bias, out, total4);
    spconv_atomic_kernel<<<KOFF * BPKF, 256, 0, stream>>>(x, w, in_idx, out_idx, out);
  }
}

// Round 14
// 262.799 us; speedup vs baseline: 1.1220x; 1.1220x over previous
//
#include <hip/hip_runtime.h>
#include <hip/hip_bf16.h>

// Rulebook sparse conv, R13 (resubmit after broker timeout): revert to
// best-measured config (R9 EXACT tier, 261.6us). R12 lesson: nt-store on
// scattered 128B rows defeats L2 partial-line merging (WRITE 169->211MB)
// and cursor-claim-in-pass1 contends; both reverted. Cached stores
// everywhere; rankl via k_count (int4); chunked LDS-stream pass2.

typedef __bf16 bf16x8_t __attribute__((ext_vector_type(8)));
typedef __bf16 bf16x4_t __attribute__((ext_vector_type(4)));
typedef __bf16 bf16x2_t __attribute__((ext_vector_type(2)));
typedef float f32x4_t __attribute__((ext_vector_type(4)));

#define KOFF 27
#define RULES 50000
#define KR (KOFF * RULES) /* 1,350,000 */
#define CIN 64
#define COUT 64
#define NIN 150000
#define NOUT 150000

// pass1 tile
#define BR1 128
#define BPK1 ((RULES + BR1 - 1) / BR1) /* 391 */
// pass2 tile
#define P2R 16
#define P2CH 256
// fallback tile
#define BRF 256
#define BPKF ((RULES + BRF - 1) / BRF) /* 196 */

// ws layout (bytes, 256-aligned)
#define OFF_OFF 0ull
#define OFF_BSUM 600064ull
#define OFF_RANK 600832ull
#define OFF_XB 6000896ull
#define OFF_VALS 25200896ull
#define WS_FULL (25200896ull + 172800000ull) /* 198.0 MB */

__device__ __forceinline__ void gload_lds16(const void* g, void* l) {
  __builtin_amdgcn_global_load_lds(
      (const __attribute__((address_space(1))) unsigned int*)g,
      (__attribute__((address_space(3))) unsigned int*)l, 16, 0, 0);
}

// ---------------- x -> bf16, fused with zeroing ----------------
__global__ __launch_bounds__(256) void k_cvt_zero(const float* __restrict__ x,
                                                  __bf16* __restrict__ xb,
                                                  int* __restrict__ cnt,
                                                  int ncnt) {
  const int i = blockIdx.x * 256 + threadIdx.x;
  if (i < NIN * CIN / 8) {
    const float4 f0 = reinterpret_cast<const float4*>(x)[i * 2];
    const float4 f1 = reinterpret_cast<const float4*>(x)[i * 2 + 1];
    bf16x8_t v;
    v[0] = (__bf16)f0.x; v[1] = (__bf16)f0.y; v[2] = (__bf16)f0.z; v[3] = (__bf16)f0.w;
    v[4] = (__bf16)f1.x; v[5] = (__bf16)f1.y; v[6] = (__bf16)f1.z; v[7] = (__bf16)f1.w;
    reinterpret_cast<bf16x8_t*>(xb)[i] = v;
  }
  if (i < ncnt) cnt[i] = 0;
}

// ---------------- sort ----------------
__global__ __launch_bounds__(256) void k_count(const int* __restrict__ out_idx,
                                               int* __restrict__ cnt,
                                               int* __restrict__ rankl) {
  const int i = blockIdx.x * 256 + threadIdx.x;
  if (i < KR / 4) {
    const int4 v = reinterpret_cast<const int4*>(out_idx)[i];
    int4 r;
    r.x = atomicAdd(&cnt[v.x], 1);
    r.y = atomicAdd(&cnt[v.y], 1);
    r.z = atomicAdd(&cnt[v.z], 1);
    r.w = atomicAdd(&cnt[v.w], 1);
    reinterpret_cast<int4*>(rankl)[i] = r;
  }
}

__global__ __launch_bounds__(1024) void k_scan1(int* __restrict__ off,
                                                int* __restrict__ bsum) {
  __shared__ int s[1024];
  const int t = threadIdx.x;
  const int i = blockIdx.x * 1024 + t;
  const int v = (i < NOUT) ? off[i] : 0;
  s[t] = v;
  __syncthreads();
#pragma unroll
  for (int d = 1; d < 1024; d <<= 1) {
    const int u = (t >= d) ? s[t - d] : 0;
    __syncthreads();
    s[t] += u;
    __syncthreads();
  }
  if (i < NOUT) off[i] = s[t] - v;
  if (t == 1023) bsum[blockIdx.x] = s[1023];
}

// per-block redundant rescan of 147 bsums, apply to off
__global__ __launch_bounds__(256) void k_scan3(int* __restrict__ off,
                                               const int* __restrict__ bsum,
                                               int nb) {
  __shared__ int s[256];
  const int t = threadIdx.x;
  const int v = (t < nb) ? bsum[t] : 0;
  s[t] = v;
  __syncthreads();
#pragma unroll
  for (int d = 1; d < 256; d <<= 1) {
    const int u = (t >= d) ? s[t - d] : 0;
    __syncthreads();
    s[t] += u;
    __syncthreads();
  }
  const int i = blockIdx.x * 256 + t;
  if (i < NOUT) {
    const int b = i >> 10;
    off[i] += s[b] - bsum[b];
  }
  if (i == 0) off[NOUT] = KR;
}

// ---------------- pass 1: bf16 gather via global_load_lds, BR=128 ----------------
__global__ __launch_bounds__(256) void pass1_bf16(
    const __bf16* __restrict__ xb, const float* __restrict__ w,
    const int* __restrict__ in_idx, const int* __restrict__ out_idx,
    const int* __restrict__ off_arr, const int* __restrict__ rankl,
    __bf16* __restrict__ vals) {
  __shared__ char lds[BR1 * 128 + 64 * 128];  // 24 KB
  __shared__ int lds_dst[BR1];
  char* const Abase = lds;
  char* const Bbase = lds + BR1 * 128;

  const int bid = blockIdx.x;
  const int k = bid / BPK1;
  const int rblk = bid - k * BPK1;
  const int rule0 = rblk * BR1;
  const int t = threadIdx.x;
  const int wid = t >> 6;
  const int lane = t & 63;

  // stage A: per-lane pre-swizzled source, linear LDS dest
  {
    const int rowInWave = lane >> 3;
    const int srcChunk = (lane & 7) ^ rowInWave;
    const int* idxBase = in_idx + (size_t)k * RULES;
#pragma unroll
    for (int it = 0; it < 4; ++it) {
      const int rbase = it * 32 + wid * 8;
      int rule = rule0 + rbase + rowInWave;
      if (rule > RULES - 1) rule = RULES - 1;  // clamp: finite data, skipped later
      const int src = idxBase[rule];
      const __bf16* gp = xb + ((size_t)src << 6) + (srcChunk << 3);
      gload_lds16(gp, Abase + rbase * 128 + lane * 16);
    }
  }

  // dst precompute (overlaps gather DMA)
  if (t < BR1) {
    const int rule = rule0 + t;
    if (rule < RULES) {
      const size_t gi = (size_t)k * RULES + rule;
      lds_dst[t] = off_arr[out_idx[gi]] + rankl[gi];
    }
  }

  // stage B: W_k^T -> LDS[o][c] bf16, swizzled
  {
    const int c = t >> 2;
    const int o0 = (t & 3) * 16;
    const float* wp = w + ((size_t)k * CIN + c) * COUT + o0;
#pragma unroll
    for (int j4 = 0; j4 < 4; ++j4) {
      const float4 f = *reinterpret_cast<const float4*>(wp + j4 * 4);
#pragma unroll
      for (int e = 0; e < 4; ++e) {
        const int o = o0 + j4 * 4 + e;
        const float val = (e == 0) ? f.x : (e == 1) ? f.y : (e == 2) ? f.z : f.w;
        const int addr = o * 128 + ((c * 2) ^ ((o & 7) << 4));
        *reinterpret_cast<__bf16*>(Bbase + addr) = (__bf16)val;
      }
    }
  }

  __syncthreads();

  const int rA = lane & 15;
  const int g = lane >> 4;

  bf16x8_t af[2][2];
  bf16x8_t bfr[4][2];
#pragma unroll
  for (int m = 0; m < 2; ++m)
#pragma unroll
    for (int kk = 0; kk < 2; ++kk) {
      const int r = wid * 32 + m * 16 + rA;
      const int colByte = (kk * 64 + g * 16) ^ ((r & 7) << 4);
      af[m][kk] = *reinterpret_cast<const bf16x8_t*>(Abase + r * 128 + colByte);
    }
#pragma unroll
  for (int n = 0; n < 4; ++n)
#pragma unroll
    for (int kk = 0; kk < 2; ++kk) {
      const int o = n * 16 + rA;
      const int colByte = (kk * 64 + g * 16) ^ ((o & 7) << 4);
      bfr[n][kk] = *reinterpret_cast<const bf16x8_t*>(Bbase + o * 128 + colByte);
    }

  __syncthreads();  // frag reads done; Abase reused for D staging

  f32x4_t acc[2][4];
#pragma unroll
  for (int m = 0; m < 2; ++m)
#pragma unroll
    for (int n = 0; n < 4; ++n)
#pragma unroll
      for (int e = 0; e < 4; ++e) acc[m][n][e] = 0.0f;

#pragma unroll
  for (int kk = 0; kk < 2; ++kk)
#pragma unroll
    for (int m = 0; m < 2; ++m)
#pragma unroll
      for (int n = 0; n < 4; ++n)
        acc[m][n] = __builtin_amdgcn_mfma_f32_16x16x32_bf16(
            af[m][kk], bfr[n][kk], acc[m][n], 0, 0, 0);

  // stage D -> LDS bf16 rows (swizzled)
  const bool evenLane = (rA & 1) == 0;
#pragma unroll
  for (int m = 0; m < 2; ++m) {
#pragma unroll
    for (int j = 0; j < 4; ++j) {
      const int rr = wid * 32 + m * 16 + g * 4 + j;
      float mine[4], other[4];
#pragma unroll
      for (int n = 0; n < 4; ++n) {
        mine[n] = acc[m][n][j];
        other[n] = __shfl_xor(mine[n], 1, 64);
      }
      const int swz = (rr & 7) << 4;
      if (evenLane) {
#pragma unroll
        for (int n = 0; n < 2; ++n) {
          bf16x2_t p; p[0] = (__bf16)mine[n]; p[1] = (__bf16)other[n];
          const int col = n * 16 + rA;
          *reinterpret_cast<bf16x2_t*>(Abase + rr * 128 + ((col * 2) ^ swz)) = p;
        }
      } else {
#pragma unroll
        for (int n = 2; n < 4; ++n) {
          bf16x2_t p; p[0] = (__bf16)other[n]; p[1] = (__bf16)mine[n];
          const int col = n * 16 + rA - 1;
          *reinterpret_cast<bf16x2_t*>(Abase + rr * 128 + ((col * 2) ^ swz)) = p;
        }
      }
    }
  }

  __syncthreads();

  // writeback: cached scatter of full 128B rows to vals[lds_dst[r]]
  {
    const int chunk = t & 7;
    const int r0 = t >> 3;
#pragma unroll
    for (int pass = 0; pass < 4; ++pass) {
      const int r = r0 + pass * 32;
      const int rule = rule0 + r;
      if (rule < RULES) {
        const int dst = lds_dst[r];
        const bf16x8_t v = *reinterpret_cast<const bf16x8_t*>(
            Abase + r * 128 + ((chunk * 16) ^ ((r & 7) << 4)));
        *reinterpret_cast<bf16x8_t*>(vals + (size_t)dst * COUT + chunk * 8) = v;
      }
    }
  }
}

// ---------------- pass 2: chunked LDS-stream, register accumulate ----------
__global__ __launch_bounds__(256) void pass2_kernel(
    const __bf16* __restrict__ vals, const int* __restrict__ off,
    const float* __restrict__ bias, float* __restrict__ out) {
  __shared__ __bf16 buf[P2CH * COUT];  // 32 KB
  __shared__ int soff[P2R + 1];

  const int t = threadIdx.x;
  const int row0 = blockIdx.x * P2R;

  if (t <= P2R) {
    int r = row0 + t;
    if (r > NOUT) r = NOUT;
    soff[t] = off[r];
  }
  __syncthreads();

  const int S = soff[0];
  const int E = soff[P2R];
  const int rloc = t >> 4;
  const int l16 = t & 15;
  const int r0 = soff[rloc];
  const int r1 = soff[rloc + 1];

  const float4 b = reinterpret_cast<const float4*>(bias)[l16];
  float a0 = b.x, a1 = b.y, a2 = b.z, a3 = b.w;

  for (int base = S; base < E; base += P2CH) {
    const int n = min(P2CH, E - base);
    for (int u = t; u < n * 8; u += 256)
      gload_lds16(vals + ((size_t)base << 6) + (size_t)u * 8,
                  (char*)buf + (size_t)u * 16);
    __syncthreads();

    const int js = (r0 > base) ? r0 : base;
    const int je = (r1 < base + n) ? r1 : (base + n);
    const char* bp = (const char*)buf + (size_t)(js - base) * 128 + l16 * 8;
    for (int j = js; j < je; ++j, bp += 128) {
      const bf16x4_t v = *reinterpret_cast<const bf16x4_t*>(bp);
      a0 += (float)v[0];
      a1 += (float)v[1];
      a2 += (float)v[2];
      a3 += (float)v[3];
    }
    __syncthreads();
  }

  const int row = row0 + rloc;
  if (row < NOUT)
    reinterpret_cast<float4*>(out + (size_t)row * COUT)[l16] =
        make_float4(a0, a1, a2, a3);
}

// ---------------- fallback (tiny ws): atomic scatter ----------------
__global__ __launch_bounds__(256) void init_out_kernel(
    const float* __restrict__ bias, float* __restrict__ out, int total4) {
  const int i = blockIdx.x * blockDim.x + threadIdx.x;
  if (i < total4) {
    const float4 v = reinterpret_cast<const float4*>(bias)[i & 15];
    reinterpret_cast<float4*>(out)[i] = v;
  }
}

__global__ __launch_bounds__(256) void spconv_atomic_kernel(
    const float* __restrict__ x, const float* __restrict__ w,
    const int* __restrict__ in_idx, const int* __restrict__ out_idx,
    float* __restrict__ out) {
  __shared__ char lds[256 * 128 + 64 * 128];
  char* const Abase = lds;
  char* const Bbase = lds + 256 * 128;

  const int bid = blockIdx.x;
  const int k = bid / BPKF;
  const int rblk = bid - k * BPKF;
  const int rule0 = rblk * BRF;
  const int t = threadIdx.x;

  {
    const int chunk = t & 7;
    const int r0 = t >> 3;
#pragma unroll
    for (int pass = 0; pass < 8; ++pass) {
      const int r = r0 + pass * 32;
      const int rule = rule0 + r;
      bf16x8_t v;
      if (rule < RULES) {
        const int src = in_idx[(size_t)k * RULES + rule];
        const float* p = x + (size_t)src * CIN + chunk * 8;
        const float4 f0 = *reinterpret_cast<const float4*>(p);
        const float4 f1 = *reinterpret_cast<const float4*>(p + 4);
        v[0] = (__bf16)f0.x; v[1] = (__bf16)f0.y;
        v[2] = (__bf16)f0.z; v[3] = (__bf16)f0.w;
        v[4] = (__bf16)f1.x; v[5] = (__bf16)f1.y;
        v[6] = (__bf16)f1.z; v[7] = (__bf16)f1.w;
      } else {
#pragma unroll
        for (int e = 0; e < 8; ++e) v[e] = (__bf16)0.0f;
      }
      const int colByte = (chunk * 16) ^ ((r & 7) << 4);
      *reinterpret_cast<bf16x8_t*>(Abase + r * 128 + colByte) = v;
    }
  }
  {
    const int c = t >> 2;
    const int o0 = (t & 3) * 16;
    const float* wp = w + ((size_t)k * CIN + c) * COUT + o0;
#pragma unroll
    for (int j4 = 0; j4 < 4; ++j4) {
      const float4 f = *reinterpret_cast<const float4*>(wp + j4 * 4);
#pragma unroll
      for (int e = 0; e < 4; ++e) {
        const int o = o0 + j4 * 4 + e;
        const float val = (e == 0) ? f.x : (e == 1) ? f.y : (e == 2) ? f.z : f.w;
        const int addr = o * 128 + ((c * 2) ^ ((o & 7) << 4));
        *reinterpret_cast<__bf16*>(Bbase + addr) = (__bf16)val;
      }
    }
  }
  __syncthreads();

  const int wid = t >> 6;
  const int l = t & 63;
  const int rA = l & 15;
  const int g = l >> 4;

  bf16x8_t af[4][2];
  bf16x8_t bfr[4][2];
#pragma unroll
  for (int m = 0; m < 4; ++m)
#pragma unroll
    for (int kk = 0; kk < 2; ++kk) {
      const int r = wid * 64 + m * 16 + rA;
      const int colByte = (kk * 64 + g * 16) ^ ((r & 7) << 4);
      af[m][kk] = *reinterpret_cast<const bf16x8_t*>(Abase + r * 128 + colByte);
    }
#pragma unroll
  for (int n = 0; n < 4; ++n)
#pragma unroll
    for (int kk = 0; kk < 2; ++kk) {
      const int o = n * 16 + rA;
      const int colByte = (kk * 64 + g * 16) ^ ((o & 7) << 4);
      bfr[n][kk] = *reinterpret_cast<const bf16x8_t*>(Bbase + o * 128 + colByte);
    }

  f32x4_t acc[4][4];
#pragma unroll
  for (int m = 0; m < 4; ++m)
#pragma unroll
    for (int n = 0; n < 4; ++n)
#pragma unroll
      for (int e = 0; e < 4; ++e) acc[m][n][e] = 0.0f;

#pragma unroll
  for (int kk = 0; kk < 2; ++kk)
#pragma unroll
    for (int m = 0; m < 4; ++m)
#pragma unroll
      for (int n = 0; n < 4; ++n)
        acc[m][n] = __builtin_amdgcn_mfma_f32_16x16x32_bf16(
            af[m][kk], bfr[n][kk], acc[m][n], 0, 0, 0);

#pragma unroll
  for (int m = 0; m < 4; ++m)
#pragma unroll
    for (int j = 0; j < 4; ++j) {
      const int rr = wid * 64 + m * 16 + g * 4 + j;
      const int rule = rule0 + rr;
      if (rule < RULES) {
        const int orow = out_idx[(size_t)k * RULES + rule];
        float* op = out + (size_t)orow * COUT + rA;
#pragma unroll
        for (int n = 0; n < 4; ++n) atomicAdd(op + n * 16, acc[m][n][j]);
      }
    }
}

// ---------------- launch ----------------
extern "C" void kernel_launch(void* const* d_in, const int* in_sizes, int n_in,
                              void* d_out, int out_size, void* d_ws, size_t ws_size,
                              hipStream_t stream) {
  const float* x = (const float*)d_in[0];
  const float* w = (const float*)d_in[1];
  const float* bias = (const float*)d_in[2];
  const int* in_idx = (const int*)d_in[3];
  const int* out_idx = (const int*)d_in[4];
  float* out = (float*)d_out;

  if (ws_size >= WS_FULL) {
    char* ws = (char*)d_ws;
    int* off = (int*)(ws + OFF_OFF);
    int* bsum = (int*)(ws + OFF_BSUM);
    int* rankl = (int*)(ws + OFF_RANK);
    __bf16* xb = (__bf16*)(ws + OFF_XB);
    __bf16* vals = (__bf16*)(ws + OFF_VALS);

    const int nb1 = (NOUT + 1023) / 1024;  // 147
    k_cvt_zero<<<(NIN * CIN / 8 + 255) / 256, 256, 0, stream>>>(x, xb, off,
                                                                NOUT + 1);
    k_count<<<(KR / 4 + 255) / 256, 256, 0, stream>>>(out_idx, off, rankl);
    k_scan1<<<nb1, 1024, 0, stream>>>(off, bsum);
    k_scan3<<<(NOUT + 255) / 256, 256, 0, stream>>>(off, bsum, nb1);
    pass1_bf16<<<KOFF * BPK1, 256, 0, stream>>>(xb, w, in_idx, out_idx, off,
                                                rankl, vals);
    pass2_kernel<<<(NOUT + P2R - 1) / P2R, 256, 0, stream>>>(vals, off, bias, out);
  } else {
    const int total4 = NOUT * COUT / 4;
    init_out_kernel<<<(total4 + 255) / 256, 256, 0, stream>>>(bias, out, total4);
    spconv_atomic_kernel<<<KOFF * BPKF, 256, 0, stream>>>(x, w, in_idx, out_idx, out);
  }
}